// Round 1
// baseline (140.131 us; speedup 1.0000x reference)
//
#include <hip/hip_runtime.h>

#pragma clang fp contract(off)

#define N_PTS   16384
#define N_SEEDS 20
#define KP1     11      // K+1, K=10

// ---------------------------------------------------------------------------
// Kernel 1: farthest point sampling. One block per batch, 1024 threads,
// 16 points per thread held in registers. Block-wide argmax with
// first-index tie-break (matches jnp.argmax).
// ---------------------------------------------------------------------------
__global__ __launch_bounds__(1024) void fps_kernel(const float* __restrict__ pcs,
                                                   int* __restrict__ seeds) {
    const int b = blockIdx.x;
    const float* __restrict__ P = pcs + (size_t)b * N_PTS * 3;
    const int t = threadIdx.x;

    float px[16], py[16], pz[16], dist[16];
#pragma unroll
    for (int k = 0; k < 16; ++k) {
        const int idx = t + k * 1024;
        px[k] = P[idx * 3 + 0];
        py[k] = P[idx * 3 + 1];
        pz[k] = P[idx * 3 + 2];
        dist[k] = 1e10f;
    }

    __shared__ float s_val[16];
    __shared__ int   s_idx[16];
    __shared__ int   s_far;

    int farthest = 0;
    for (int it = 0; it < N_SEEDS; ++it) {
        if (t == 0) seeds[b * N_SEEDS + it] = farthest;  // record OLD farthest

        const float cx = P[farthest * 3 + 0];
        const float cy = P[farthest * 3 + 1];
        const float cz = P[farthest * 3 + 2];

        float bestv = -1.0f;
        int   besti = 0;
#pragma unroll
        for (int k = 0; k < 16; ++k) {
            const float dx = px[k] - cx;
            const float dy = py[k] - cy;
            const float dz = pz[k] - cz;
            const float d  = (dx * dx + dy * dy) + dz * dz;  // no-fma, L-to-R
            const float nd = fminf(dist[k], d);
            dist[k] = nd;
            // idx increases with k, so strict > keeps first-index semantics
            if (nd > bestv) { bestv = nd; besti = t + k * 1024; }
        }

        // wave (64-lane) argmax, lower index wins ties
        for (int off = 32; off > 0; off >>= 1) {
            const float ov = __shfl_xor(bestv, off);
            const int   oi = __shfl_xor(besti, off);
            if (ov > bestv || (ov == bestv && oi < besti)) { bestv = ov; besti = oi; }
        }
        const int wid = t >> 6;
        if ((t & 63) == 0) { s_val[wid] = bestv; s_idx[wid] = besti; }
        __syncthreads();
        if (t < 64) {
            float v = (t < 16) ? s_val[t] : -1.0f;
            int   i = (t < 16) ? s_idx[t] : 0;
            for (int off = 8; off > 0; off >>= 1) {
                const float ov = __shfl_xor(v, off);
                const int   oi = __shfl_xor(i, off);
                if (ov > v || (ov == v && oi < i)) { v = ov; i = oi; }
            }
            if (t == 0) s_far = i;
        }
        __syncthreads();
        farthest = s_far;
    }
}

// ---------------------------------------------------------------------------
// Kernel 2: per (batch, seed) find the 11 smallest euclidean distances.
// 256 threads; each thread keeps its own sorted top-11 via a static-index
// min/max ladder (no scratch spill), then block merge in LDS with 11
// masked-min passes. Only values are kept (ties irrelevant).
// ---------------------------------------------------------------------------
__global__ __launch_bounds__(256) void knn_kernel(const float* __restrict__ pcs,
                                                  const int* __restrict__ seeds,
                                                  float* __restrict__ topd) {
    const int blk = blockIdx.x;
    const int b   = blk / N_SEEDS;
    const float* __restrict__ P = pcs + (size_t)b * N_PTS * 3;
    const int sid = seeds[blk];
    const float cx = P[sid * 3 + 0];
    const float cy = P[sid * 3 + 1];
    const float cz = P[sid * 3 + 2];
    const int t = threadIdx.x;

    float top[KP1];
#pragma unroll
    for (int j = 0; j < KP1; ++j) top[j] = 3e38f;

    for (int j = 0; j < N_PTS / 256; ++j) {
        const int idx = t + j * 256;
        const float dx = P[idx * 3 + 0] - cx;
        const float dy = P[idx * 3 + 1] - cy;
        const float dz = P[idx * 3 + 2] - cz;
        const float v  = sqrtf((dx * dx + dy * dy) + dz * dz);
        if (v < top[KP1 - 1]) {
            float x = v;
#pragma unroll
            for (int p = 0; p < KP1; ++p) {      // bubble insert, static idx
                const float lo = fminf(top[p], x);
                const float hi = fmaxf(top[p], x);
                top[p] = lo;
                x = hi;
            }
        }
    }

    __shared__ float arr[256 * KP1];
#pragma unroll
    for (int j = 0; j < KP1; ++j) arr[t * KP1 + j] = top[j];
    __syncthreads();

    __shared__ float s_v[4];
    __shared__ int   s_i[4];

    const int NM = 256 * KP1;
    for (int p = 0; p < KP1; ++p) {
        float bv = 3e38f;
        int   bi = -1;
        for (int j = t; j < NM; j += 256) {
            const float v = arr[j];
            if (v < bv || (v == bv && j < bi)) { bv = v; bi = j; }
        }
        for (int off = 32; off > 0; off >>= 1) {
            const float ov = __shfl_xor(bv, off);
            const int   oi = __shfl_xor(bi, off);
            if (ov < bv || (ov == bv && oi < bi)) { bv = ov; bi = oi; }
        }
        if ((t & 63) == 0) { s_v[t >> 6] = bv; s_i[t >> 6] = bi; }
        __syncthreads();
        if (t == 0) {
            float v = s_v[0]; int i = s_i[0];
            for (int w = 1; w < 4; ++w)
                if (s_v[w] < v || (s_v[w] == v && s_i[w] < i)) { v = s_v[w]; i = s_i[w]; }
            topd[blk * KP1 + p] = v;
            arr[i] = 3e38f;                       // mask the chosen element
        }
        __syncthreads();
    }
}

// ---------------------------------------------------------------------------
// Kernel 3: stats. overall_mean over [:,:,1:], per-seed means, unbiased var.
// Single block, fp64 accumulation.
// ---------------------------------------------------------------------------
__global__ __launch_bounds__(256) void stats_kernel(const float* __restrict__ topd,
                                                    float* __restrict__ out, int B) {
    const int pairs = B * N_SEEDS;
    const int total = pairs * KP1;
    const int t = threadIdx.x;
    __shared__ double red[256];
    __shared__ double om_s;

    double s1 = 0.0;
    for (int i = t; i < total; i += 256)
        if (i % KP1 != 0) s1 += (double)topd[i];
    red[t] = s1;
    __syncthreads();
    for (int off = 128; off > 0; off >>= 1) {
        if (t < off) red[t] += red[t + off];
        __syncthreads();
    }
    if (t == 0) om_s = red[0] / (double)(pairs * (KP1 - 1));
    __syncthreads();
    const double om = om_s;

    double sm = 0.0, sm2 = 0.0;
    for (int pr = t; pr < pairs; pr += 256) {
        double acc = 0.0;
        for (int j = 0; j < KP1; ++j) acc += (double)topd[pr * KP1 + j];
        const double m = acc / (om * (double)KP1);
        sm += m;
        sm2 += m * m;
    }
    red[t] = sm;
    __syncthreads();
    for (int off = 128; off > 0; off >>= 1) {
        if (t < off) red[t] += red[t + off];
        __syncthreads();
    }
    double Sm = 0.0;
    if (t == 0) Sm = red[0];
    __syncthreads();
    red[t] = sm2;
    __syncthreads();
    for (int off = 128; off > 0; off >>= 1) {
        if (t < off) red[t] += red[t + off];
        __syncthreads();
    }
    if (t == 0) {
        const double var = (red[0] - Sm * Sm / (double)pairs) / (double)(pairs - 1);
        out[0] = (float)var;
    }
}

// ---------------------------------------------------------------------------
extern "C" void kernel_launch(void* const* d_in, const int* in_sizes, int n_in,
                              void* d_out, int out_size, void* d_ws, size_t ws_size,
                              hipStream_t stream) {
    const float* pcs = (const float*)d_in[0];
    const int B = in_sizes[0] / (N_PTS * 3);

    int*   seeds = (int*)d_ws;
    float* topd  = (float*)((char*)d_ws + 8192);
    float* out   = (float*)d_out;

    fps_kernel<<<B, 1024, 0, stream>>>(pcs, seeds);
    knn_kernel<<<B * N_SEEDS, 256, 0, stream>>>(pcs, seeds, topd);
    stats_kernel<<<1, 256, 0, stream>>>(topd, out, B);
}

// Round 2
// 131.373 us; speedup vs baseline: 1.0667x; 1.0667x over previous
//
#include <hip/hip_runtime.h>

#pragma clang fp contract(off)

#define N_PTS   16384
#define N_SEEDS 20
#define KP1     11      // K+1, K=10

typedef unsigned long long u64;
typedef unsigned int       u32;

__device__ __forceinline__ u64 shfl_xor_u64(u64 v, int off) {
    int lo = __shfl_xor((int)(u32)(v & 0xffffffffull), off);
    int hi = __shfl_xor((int)(u32)(v >> 32), off);
    return ((u64)(u32)hi << 32) | (u32)lo;
}

// ---------------------------------------------------------------------------
// Kernel 1: farthest point sampling. One block per batch, 1024 threads,
// 16 consecutive points per thread in NAMED registers (spill-proof).
// Packed u64 argmax key = (float_bits(dist) << 32) | ~index  ->  exact
// jnp.argmax first-index tie-break. One barrier per iteration (parity LDS).
// ---------------------------------------------------------------------------
__global__ __launch_bounds__(1024) void fps_kernel(const float* __restrict__ pcs,
                                                   int* __restrict__ seeds) {
    const int b = blockIdx.x;
    const float* __restrict__ P  = pcs + (size_t)b * N_PTS * 3;
    const float4* __restrict__ P4 = (const float4*)P;
    const int t = threadIdx.x;

#define FDECL(i) float px##i, py##i, pz##i, dd##i = 1e10f;
    FDECL(0)  FDECL(1)  FDECL(2)  FDECL(3)
    FDECL(4)  FDECL(5)  FDECL(6)  FDECL(7)
    FDECL(8)  FDECL(9)  FDECL(10) FDECL(11)
    FDECL(12) FDECL(13) FDECL(14) FDECL(15)

    {   // 16 pts * 3 floats = 48 floats = 12 float4 per thread, contiguous
        const int f4 = t * 12;
        const float4 q0 = P4[f4+0],  q1 = P4[f4+1],  q2  = P4[f4+2];
        const float4 q3 = P4[f4+3],  q4 = P4[f4+4],  q5  = P4[f4+5];
        const float4 q6 = P4[f4+6],  q7 = P4[f4+7],  q8  = P4[f4+8];
        const float4 q9 = P4[f4+9],  q10 = P4[f4+10], q11 = P4[f4+11];
        px0 =q0.x;  py0 =q0.y;  pz0 =q0.z;
        px1 =q0.w;  py1 =q1.x;  pz1 =q1.y;
        px2 =q1.z;  py2 =q1.w;  pz2 =q2.x;
        px3 =q2.y;  py3 =q2.z;  pz3 =q2.w;
        px4 =q3.x;  py4 =q3.y;  pz4 =q3.z;
        px5 =q3.w;  py5 =q4.x;  pz5 =q4.y;
        px6 =q4.z;  py6 =q4.w;  pz6 =q5.x;
        px7 =q5.y;  py7 =q5.z;  pz7 =q5.w;
        px8 =q6.x;  py8 =q6.y;  pz8 =q6.z;
        px9 =q6.w;  py9 =q7.x;  pz9 =q7.y;
        px10=q7.z;  py10=q7.w;  pz10=q8.x;
        px11=q8.y;  py11=q8.z;  pz11=q8.w;
        px12=q9.x;  py12=q9.y;  pz12=q9.z;
        px13=q9.w;  py13=q10.x; pz13=q10.y;
        px14=q10.z; py14=q10.w; pz14=q11.x;
        px15=q11.y; py15=q11.z; pz15=q11.w;
    }

    __shared__ u64 s_key[2][16];
    int farthest = 0;

    for (int it = 0; it < N_SEEDS; ++it) {
        if (t == 0) seeds[b * N_SEEDS + it] = farthest;   // record OLD farthest

        const int fi = __builtin_amdgcn_readfirstlane(farthest);
        const float cx = P[fi*3], cy = P[fi*3+1], cz = P[fi*3+2];

        u64 bk = 0ull;
#define FSTEP(i) { const float dx = px##i - cx, dy = py##i - cy, dz = pz##i - cz; \
        const float d  = (dx*dx + dy*dy) + dz*dz; \
        const float nd = fminf(dd##i, d); dd##i = nd; \
        const u64 key = ((u64)__float_as_uint(nd) << 32) | (u32)(~(u32)(t*16 + (i))); \
        if (key > bk) bk = key; }
        FSTEP(0)  FSTEP(1)  FSTEP(2)  FSTEP(3)
        FSTEP(4)  FSTEP(5)  FSTEP(6)  FSTEP(7)
        FSTEP(8)  FSTEP(9)  FSTEP(10) FSTEP(11)
        FSTEP(12) FSTEP(13) FSTEP(14) FSTEP(15)

        // wave (64-lane) max
        for (int off = 32; off; off >>= 1) {
            const u64 ok = shfl_xor_u64(bk, off);
            if (ok > bk) bk = ok;
        }
        const int par = it & 1;
        if ((t & 63) == 0) s_key[par][t >> 6] = bk;
        __syncthreads();
        {   // every wave reduces the 16 per-wave keys itself: no 2nd barrier
            const int lane = t & 63;
            u64 k2 = (lane < 16) ? s_key[par][lane] : 0ull;
            for (int off = 8; off; off >>= 1) {
                const u64 ok = shfl_xor_u64(k2, off);
                if (ok > k2) k2 = ok;
            }
            const u32 blo = (u32)__shfl((int)(u32)(k2 & 0xffffffffull), 0);
            farthest = (int)(~blo);
        }
    }
}

// ---------------------------------------------------------------------------
// Kernel 2: per (batch, seed) 11 smallest squared distances; sqrt at the end.
// 256 threads, 64 pts/thread via float4 loads; NAMED-register top-11 ladder;
// barrier-free single-wave merge via unique keys and ascending extraction.
// ---------------------------------------------------------------------------
__global__ __launch_bounds__(256) void knn_kernel(const float* __restrict__ pcs,
                                                  const int* __restrict__ seeds,
                                                  float* __restrict__ topd) {
    const int blk = blockIdx.x;
    const int b   = blk / N_SEEDS;
    const float* __restrict__ P  = pcs + (size_t)b * N_PTS * 3;
    const float4* __restrict__ P4 = (const float4*)P;
    const int t = threadIdx.x;
    const int sid = seeds[blk];
    const float cx = P[sid*3], cy = P[sid*3+1], cz = P[sid*3+2];

    float t0 = 3e38f, t1 = 3e38f, t2 = 3e38f, t3 = 3e38f, t4 = 3e38f,
          t5 = 3e38f, t6 = 3e38f, t7 = 3e38f, t8 = 3e38f, t9 = 3e38f,
          t10 = 3e38f;

#define KNN_INS(v) do { float x = (v); if (x < t10) { float lo; \
    lo = fminf(t0, x); x = fmaxf(t0, x); t0 = lo; \
    lo = fminf(t1, x); x = fmaxf(t1, x); t1 = lo; \
    lo = fminf(t2, x); x = fmaxf(t2, x); t2 = lo; \
    lo = fminf(t3, x); x = fmaxf(t3, x); t3 = lo; \
    lo = fminf(t4, x); x = fmaxf(t4, x); t4 = lo; \
    lo = fminf(t5, x); x = fmaxf(t5, x); t5 = lo; \
    lo = fminf(t6, x); x = fmaxf(t6, x); t6 = lo; \
    lo = fminf(t7, x); x = fmaxf(t7, x); t7 = lo; \
    lo = fminf(t8, x); x = fmaxf(t8, x); t8 = lo; \
    lo = fminf(t9, x); x = fmaxf(t9, x); t9 = lo; \
    t10 = fminf(t10, x); } } while (0)

#pragma unroll 2
    for (int c = 0; c < N_PTS / (256 * 4); ++c) {   // 16 chunks of 4 pts
        const int i4 = (c * 256 + t) * 3;
        const float4 a = P4[i4], bq = P4[i4 + 1], cq = P4[i4 + 2];
        { const float dx=a.x -cx, dy=a.y -cy, dz=a.z -cz; KNN_INS((dx*dx+dy*dy)+dz*dz); }
        { const float dx=a.w -cx, dy=bq.x-cy, dz=bq.y-cz; KNN_INS((dx*dx+dy*dy)+dz*dz); }
        { const float dx=bq.z-cx, dy=bq.w-cy, dz=cq.x-cz; KNN_INS((dx*dx+dy*dy)+dz*dz); }
        { const float dx=cq.y-cx, dy=cq.z-cy, dz=cq.w-cz; KNN_INS((dx*dx+dy*dy)+dz*dz); }
    }

    __shared__ float arr[256 * KP1];
    arr[t*KP1+0] = t0;  arr[t*KP1+1] = t1;  arr[t*KP1+2] = t2;
    arr[t*KP1+3] = t3;  arr[t*KP1+4] = t4;  arr[t*KP1+5] = t5;
    arr[t*KP1+6] = t6;  arr[t*KP1+7] = t7;  arr[t*KP1+8] = t8;
    arr[t*KP1+9] = t9;  arr[t*KP1+10] = t10;
    __syncthreads();

    if (t < 64) {
        // unique keys: (bits(d2)<<32) | (j+1)  -> min-extraction in ascending
        // key order, masking by "key > prev". No LDS writes, no barriers.
        u64 prev = 0ull;
        for (int p = 0; p < KP1; ++p) {
            u64 bk = ~0ull;
            for (int j = t; j < 256 * KP1; j += 64) {
                const u64 key = ((u64)__float_as_uint(arr[j]) << 32) | (u32)(j + 1);
                if (key > prev && key < bk) bk = key;
            }
            for (int off = 32; off; off >>= 1) {
                const u64 ok = shfl_xor_u64(bk, off);
                if (ok < bk) bk = ok;
            }
            prev = bk;   // all 64 lanes agree after butterfly
            if (t == 0)
                topd[blk * KP1 + p] = sqrtf(__uint_as_float((u32)(bk >> 32)));
        }
    }
}

// ---------------------------------------------------------------------------
// Kernel 3: stats. overall_mean over [:,:,1:], per-seed means, unbiased var.
// ---------------------------------------------------------------------------
__global__ __launch_bounds__(256) void stats_kernel(const float* __restrict__ topd,
                                                    float* __restrict__ out, int B) {
    const int pairs = B * N_SEEDS;
    const int total = pairs * KP1;
    const int t = threadIdx.x;
    __shared__ double red[256];
    __shared__ double om_s;

    double s1 = 0.0;
    for (int i = t; i < total; i += 256)
        if (i % KP1 != 0) s1 += (double)topd[i];
    red[t] = s1;
    __syncthreads();
    for (int off = 128; off > 0; off >>= 1) {
        if (t < off) red[t] += red[t + off];
        __syncthreads();
    }
    if (t == 0) om_s = red[0] / (double)(pairs * (KP1 - 1));
    __syncthreads();
    const double om = om_s;

    double sm = 0.0, sm2 = 0.0;
    for (int pr = t; pr < pairs; pr += 256) {
        double acc = 0.0;
        for (int j = 0; j < KP1; ++j) acc += (double)topd[pr * KP1 + j];
        const double m = acc / (om * (double)KP1);
        sm += m;
        sm2 += m * m;
    }
    red[t] = sm;
    __syncthreads();
    for (int off = 128; off > 0; off >>= 1) {
        if (t < off) red[t] += red[t + off];
        __syncthreads();
    }
    double Sm = 0.0;
    if (t == 0) Sm = red[0];
    __syncthreads();
    red[t] = sm2;
    __syncthreads();
    for (int off = 128; off > 0; off >>= 1) {
        if (t < off) red[t] += red[t + off];
        __syncthreads();
    }
    if (t == 0) {
        const double var = (red[0] - Sm * Sm / (double)pairs) / (double)(pairs - 1);
        out[0] = (float)var;
    }
}

// ---------------------------------------------------------------------------
extern "C" void kernel_launch(void* const* d_in, const int* in_sizes, int n_in,
                              void* d_out, int out_size, void* d_ws, size_t ws_size,
                              hipStream_t stream) {
    const float* pcs = (const float*)d_in[0];
    const int B = in_sizes[0] / (N_PTS * 3);

    int*   seeds = (int*)d_ws;
    float* topd  = (float*)((char*)d_ws + 8192);
    float* out   = (float*)d_out;

    fps_kernel<<<B, 1024, 0, stream>>>(pcs, seeds);
    knn_kernel<<<B * N_SEEDS, 256, 0, stream>>>(pcs, seeds, topd);
    stats_kernel<<<1, 256, 0, stream>>>(topd, out, B);
}

// Round 3
// 130.547 us; speedup vs baseline: 1.0734x; 1.0063x over previous
//
#include <hip/hip_runtime.h>

#pragma clang fp contract(off)

#define N_PTS   16384
#define N_SEEDS 20
#define KP1     11      // K+1, K=10

typedef unsigned long long u64;
typedef unsigned int       u32;

__device__ __forceinline__ u64 shfl_xor_u64(u64 v, int off) {
    int lo = __shfl_xor((int)(u32)(v & 0xffffffffull), off);
    int hi = __shfl_xor((int)(u32)(v >> 32), off);
    return ((u64)(u32)hi << 32) | (u32)lo;
}

// ---------------------------------------------------------------------------
// Kernel 1: farthest point sampling. One block per batch, 1024 threads,
// 16 consecutive points per thread in NAMED registers. Selection matches
// jnp.argmax exactly (first index on ties at every level). Winner coords
// ride through the reduction -> no dependent global centroid load.
// One barrier per iteration (parity-double-buffered LDS).
// ---------------------------------------------------------------------------
__global__ __launch_bounds__(1024) void fps_kernel(const float* __restrict__ pcs,
                                                   int* __restrict__ seeds) {
    const int b = blockIdx.x;
    const float* __restrict__ P  = pcs + (size_t)b * N_PTS * 3;
    const float4* __restrict__ P4 = (const float4*)P;
    const int t    = threadIdx.x;
    const int lane = t & 63;
    const int wid  = t >> 6;

#define FDECL(i) float px##i, py##i, pz##i, dd##i = 1e10f;
    FDECL(0)  FDECL(1)  FDECL(2)  FDECL(3)
    FDECL(4)  FDECL(5)  FDECL(6)  FDECL(7)
    FDECL(8)  FDECL(9)  FDECL(10) FDECL(11)
    FDECL(12) FDECL(13) FDECL(14) FDECL(15)

    {   // 16 pts * 3 floats = 48 floats = 12 float4 per thread, contiguous
        const int f4 = t * 12;
        const float4 q0 = P4[f4+0],  q1 = P4[f4+1],  q2  = P4[f4+2];
        const float4 q3 = P4[f4+3],  q4 = P4[f4+4],  q5  = P4[f4+5];
        const float4 q6 = P4[f4+6],  q7 = P4[f4+7],  q8  = P4[f4+8];
        const float4 q9 = P4[f4+9],  q10 = P4[f4+10], q11 = P4[f4+11];
        px0 =q0.x;  py0 =q0.y;  pz0 =q0.z;
        px1 =q0.w;  py1 =q1.x;  pz1 =q1.y;
        px2 =q1.z;  py2 =q1.w;  pz2 =q2.x;
        px3 =q2.y;  py3 =q2.z;  pz3 =q2.w;
        px4 =q3.x;  py4 =q3.y;  pz4 =q3.z;
        px5 =q3.w;  py5 =q4.x;  pz5 =q4.y;
        px6 =q4.z;  py6 =q4.w;  pz6 =q5.x;
        px7 =q5.y;  py7 =q5.z;  pz7 =q5.w;
        px8 =q6.x;  py8 =q6.y;  pz8 =q6.z;
        px9 =q6.w;  py9 =q7.x;  pz9 =q7.y;
        px10=q7.z;  py10=q7.w;  pz10=q8.x;
        px11=q8.y;  py11=q8.z;  pz11=q8.w;
        px12=q9.x;  py12=q9.y;  pz12=q9.z;
        px13=q9.w;  py13=q10.x; pz13=q10.y;
        px14=q10.z; py14=q10.w; pz14=q11.x;
        px15=q11.y; py15=q11.z; pz15=q11.w;
    }

    __shared__ u64   s_key[2][16];
    __shared__ float s_cx[2][16], s_cy[2][16], s_cz[2][16];

    float cx = P[0], cy = P[1], cz = P[2];   // centroid of seed 0 (index 0)
    int farthest = 0;

    for (int it = 0; it < N_SEEDS; ++it) {
        if (t == 0) seeds[b * N_SEEDS + it] = farthest;   // record OLD farthest

        float bestv = -1.0f, bx = 0.f, by = 0.f, bz = 0.f;
        int   besti = 0;
#define FSTEP(i) { const float dx = px##i - cx, dy = py##i - cy, dz = pz##i - cz; \
        const float d  = (dx*dx + dy*dy) + dz*dz; \
        const float nd = fminf(dd##i, d); dd##i = nd; \
        if (nd > bestv) { bestv = nd; besti = t*16 + (i); \
                          bx = px##i; by = py##i; bz = pz##i; } }
        FSTEP(0)  FSTEP(1)  FSTEP(2)  FSTEP(3)
        FSTEP(4)  FSTEP(5)  FSTEP(6)  FSTEP(7)
        FSTEP(8)  FSTEP(9)  FSTEP(10) FSTEP(11)
        FSTEP(12) FSTEP(13) FSTEP(14) FSTEP(15)

        // wave max (float), then locate lowest lane holding it (= lowest index)
        float wmax = bestv;
        for (int off = 32; off; off >>= 1)
            wmax = fmaxf(wmax, __shfl_xor(wmax, off));
        const u64 msk = __ballot(bestv == wmax);
        const int low = __ffsll((unsigned long long)msk) - 1;
        const int wi  = __shfl(besti, low);
        const float wx = __shfl(bx, low);
        const float wy = __shfl(by, low);
        const float wz = __shfl(bz, low);

        const int par = it & 1;
        if (lane == 0) {
            s_key[par][wid] = ((u64)__float_as_uint(wmax) << 32) | (u32)(~(u32)wi);
            s_cx[par][wid] = wx; s_cy[par][wid] = wy; s_cz[par][wid] = wz;
        }
        __syncthreads();

        // every lane reduces the 16 wave keys (xor-butterfly within 16-groups)
        u64 k = s_key[par][lane & 15];
        for (int off = 8; off; off >>= 1) {
            const u64 o = shfl_xor_u64(k, off);
            if (o > k) k = o;
        }
        const int widx = (int)(~(u32)k);    // winning point index (lowest on ties)
        farthest = widx;
        const int ww = widx >> 10;          // wave that owns it (1024 idx / wave)
        cx = s_cx[par][ww]; cy = s_cy[par][ww]; cz = s_cz[par][ww];
    }
}

// ---------------------------------------------------------------------------
// Kernel 2: per (batch, seed) 11 smallest squared distances; sqrt at the end.
// XCD-aware bid mapping: all 20 seed-blocks of batch b land on XCD (b%8),
// so each XCD's L2 holds only its 8 batches (1.5 MB) -> ~6x less L2-fill.
// ---------------------------------------------------------------------------
__global__ __launch_bounds__(256) void knn_kernel(const float* __restrict__ pcs,
                                                  const int* __restrict__ seeds,
                                                  float* __restrict__ topd) {
    const int bid = blockIdx.x;
    const int x   = bid & 7;          // XCD slot
    const int q   = bid >> 3;
    const int s   = q % 20;
    const int b   = x + 8 * (q / 20);
    const int blk = b * N_SEEDS + s;

    const float* __restrict__ P  = pcs + (size_t)b * N_PTS * 3;
    const float4* __restrict__ P4 = (const float4*)P;
    const int t = threadIdx.x;
    const int sid = seeds[blk];
    const float cx = P[sid*3], cy = P[sid*3+1], cz = P[sid*3+2];

    float t0 = 3e38f, t1 = 3e38f, t2 = 3e38f, t3 = 3e38f, t4 = 3e38f,
          t5 = 3e38f, t6 = 3e38f, t7 = 3e38f, t8 = 3e38f, t9 = 3e38f,
          t10 = 3e38f;

#define KNN_INS(v) do { float xx = (v); if (xx < t10) { float lo; \
    lo = fminf(t0, xx); xx = fmaxf(t0, xx); t0 = lo; \
    lo = fminf(t1, xx); xx = fmaxf(t1, xx); t1 = lo; \
    lo = fminf(t2, xx); xx = fmaxf(t2, xx); t2 = lo; \
    lo = fminf(t3, xx); xx = fmaxf(t3, xx); t3 = lo; \
    lo = fminf(t4, xx); xx = fmaxf(t4, xx); t4 = lo; \
    lo = fminf(t5, xx); xx = fmaxf(t5, xx); t5 = lo; \
    lo = fminf(t6, xx); xx = fmaxf(t6, xx); t6 = lo; \
    lo = fminf(t7, xx); xx = fmaxf(t7, xx); t7 = lo; \
    lo = fminf(t8, xx); xx = fmaxf(t8, xx); t8 = lo; \
    lo = fminf(t9, xx); xx = fmaxf(t9, xx); t9 = lo; \
    t10 = fminf(t10, xx); } } while (0)

#pragma unroll 2
    for (int c = 0; c < N_PTS / (256 * 4); ++c) {   // 16 chunks of 4 pts
        const int i4 = (c * 256 + t) * 3;
        const float4 a = P4[i4], bq = P4[i4 + 1], cq = P4[i4 + 2];
        { const float dx=a.x -cx, dy=a.y -cy, dz=a.z -cz; KNN_INS((dx*dx+dy*dy)+dz*dz); }
        { const float dx=a.w -cx, dy=bq.x-cy, dz=bq.y-cz; KNN_INS((dx*dx+dy*dy)+dz*dz); }
        { const float dx=bq.z-cx, dy=bq.w-cy, dz=cq.x-cz; KNN_INS((dx*dx+dy*dy)+dz*dz); }
        { const float dx=cq.y-cx, dy=cq.z-cy, dz=cq.w-cz; KNN_INS((dx*dx+dy*dy)+dz*dz); }
    }

    __shared__ float arr[256 * KP1];
    arr[t*KP1+0] = t0;  arr[t*KP1+1] = t1;  arr[t*KP1+2] = t2;
    arr[t*KP1+3] = t3;  arr[t*KP1+4] = t4;  arr[t*KP1+5] = t5;
    arr[t*KP1+6] = t6;  arr[t*KP1+7] = t7;  arr[t*KP1+8] = t8;
    arr[t*KP1+9] = t9;  arr[t*KP1+10] = t10;
    __syncthreads();

    if (t < 64) {
        // unique keys: (bits(d2)<<32) | (j+1)  -> min-extraction in ascending
        // key order, masking by "key > prev". No LDS writes, no barriers.
        u64 prev = 0ull;
        for (int p = 0; p < KP1; ++p) {
            u64 bk = ~0ull;
            for (int j = t; j < 256 * KP1; j += 64) {
                const u64 key = ((u64)__float_as_uint(arr[j]) << 32) | (u32)(j + 1);
                if (key > prev && key < bk) bk = key;
            }
            for (int off = 32; off; off >>= 1) {
                const u64 ok = shfl_xor_u64(bk, off);
                if (ok < bk) bk = ok;
            }
            prev = bk;   // all 64 lanes agree after butterfly
            if (t == 0)
                topd[blk * KP1 + p] = sqrtf(__uint_as_float((u32)(bk >> 32)));
        }
    }
}

// ---------------------------------------------------------------------------
// Kernel 3: stats. overall_mean over [:,:,1:], per-seed means, unbiased var.
// ---------------------------------------------------------------------------
__global__ __launch_bounds__(256) void stats_kernel(const float* __restrict__ topd,
                                                    float* __restrict__ out, int B) {
    const int pairs = B * N_SEEDS;
    const int total = pairs * KP1;
    const int t = threadIdx.x;
    __shared__ double red[256];
    __shared__ double om_s;

    double s1 = 0.0;
    for (int i = t; i < total; i += 256)
        if (i % KP1 != 0) s1 += (double)topd[i];
    red[t] = s1;
    __syncthreads();
    for (int off = 128; off > 0; off >>= 1) {
        if (t < off) red[t] += red[t + off];
        __syncthreads();
    }
    if (t == 0) om_s = red[0] / (double)(pairs * (KP1 - 1));
    __syncthreads();
    const double om = om_s;

    double sm = 0.0, sm2 = 0.0;
    for (int pr = t; pr < pairs; pr += 256) {
        double acc = 0.0;
        for (int j = 0; j < KP1; ++j) acc += (double)topd[pr * KP1 + j];
        const double m = acc / (om * (double)KP1);
        sm += m;
        sm2 += m * m;
    }
    red[t] = sm;
    __syncthreads();
    for (int off = 128; off > 0; off >>= 1) {
        if (t < off) red[t] += red[t + off];
        __syncthreads();
    }
    double Sm = 0.0;
    if (t == 0) Sm = red[0];
    __syncthreads();
    red[t] = sm2;
    __syncthreads();
    for (int off = 128; off > 0; off >>= 1) {
        if (t < off) red[t] += red[t + off];
        __syncthreads();
    }
    if (t == 0) {
        const double var = (red[0] - Sm * Sm / (double)pairs) / (double)(pairs - 1);
        out[0] = (float)var;
    }
}

// ---------------------------------------------------------------------------
extern "C" void kernel_launch(void* const* d_in, const int* in_sizes, int n_in,
                              void* d_out, int out_size, void* d_ws, size_t ws_size,
                              hipStream_t stream) {
    const float* pcs = (const float*)d_in[0];
    const int B = in_sizes[0] / (N_PTS * 3);

    int*   seeds = (int*)d_ws;
    float* topd  = (float*)((char*)d_ws + 8192);
    float* out   = (float*)d_out;

    fps_kernel<<<B, 1024, 0, stream>>>(pcs, seeds);
    knn_kernel<<<B * N_SEEDS, 256, 0, stream>>>(pcs, seeds, topd);
    stats_kernel<<<1, 256, 0, stream>>>(topd, out, B);
}

// Round 4
// 84.789 us; speedup vs baseline: 1.6527x; 1.5397x over previous
//
#include <hip/hip_runtime.h>

#pragma clang fp contract(off)

#define N_PTS   16384
#define N_SEEDS 20
#define KP1     11      // K+1, K=10
#define NBIN    2048    // float-bit radix bins: bits(d2) >> 20
#define CAP     2048    // candidate buffer capacity

typedef unsigned long long u64;
typedef unsigned int       u32;

__device__ __forceinline__ u64 shfl_xor_u64(u64 v, int off) {
    int lo = __shfl_xor((int)(u32)(v & 0xffffffffull), off);
    int hi = __shfl_xor((int)(u32)(v >> 32), off);
    return ((u64)(u32)hi << 32) | (u32)lo;
}

// ---------------------------------------------------------------------------
// Kernel 1: farthest point sampling (UNCHANGED from round 2/3 — absmax 0.0).
// ---------------------------------------------------------------------------
__global__ __launch_bounds__(1024) void fps_kernel(const float* __restrict__ pcs,
                                                   int* __restrict__ seeds) {
    const int b = blockIdx.x;
    const float* __restrict__ P  = pcs + (size_t)b * N_PTS * 3;
    const float4* __restrict__ P4 = (const float4*)P;
    const int t    = threadIdx.x;
    const int lane = t & 63;
    const int wid  = t >> 6;

#define FDECL(i) float px##i, py##i, pz##i, dd##i = 1e10f;
    FDECL(0)  FDECL(1)  FDECL(2)  FDECL(3)
    FDECL(4)  FDECL(5)  FDECL(6)  FDECL(7)
    FDECL(8)  FDECL(9)  FDECL(10) FDECL(11)
    FDECL(12) FDECL(13) FDECL(14) FDECL(15)

    {   // 16 pts * 3 floats = 48 floats = 12 float4 per thread, contiguous
        const int f4 = t * 12;
        const float4 q0 = P4[f4+0],  q1 = P4[f4+1],  q2  = P4[f4+2];
        const float4 q3 = P4[f4+3],  q4 = P4[f4+4],  q5  = P4[f4+5];
        const float4 q6 = P4[f4+6],  q7 = P4[f4+7],  q8  = P4[f4+8];
        const float4 q9 = P4[f4+9],  q10 = P4[f4+10], q11 = P4[f4+11];
        px0 =q0.x;  py0 =q0.y;  pz0 =q0.z;
        px1 =q0.w;  py1 =q1.x;  pz1 =q1.y;
        px2 =q1.z;  py2 =q1.w;  pz2 =q2.x;
        px3 =q2.y;  py3 =q2.z;  pz3 =q2.w;
        px4 =q3.x;  py4 =q3.y;  pz4 =q3.z;
        px5 =q3.w;  py5 =q4.x;  pz5 =q4.y;
        px6 =q4.z;  py6 =q4.w;  pz6 =q5.x;
        px7 =q5.y;  py7 =q5.z;  pz7 =q5.w;
        px8 =q6.x;  py8 =q6.y;  pz8 =q6.z;
        px9 =q6.w;  py9 =q7.x;  pz9 =q7.y;
        px10=q7.z;  py10=q7.w;  pz10=q8.x;
        px11=q8.y;  py11=q8.z;  pz11=q8.w;
        px12=q9.x;  py12=q9.y;  pz12=q9.z;
        px13=q9.w;  py13=q10.x; pz13=q10.y;
        px14=q10.z; py14=q10.w; pz14=q11.x;
        px15=q11.y; py15=q11.z; pz15=q11.w;
    }

    __shared__ u64   s_key[2][16];
    __shared__ float s_cx[2][16], s_cy[2][16], s_cz[2][16];

    float cx = P[0], cy = P[1], cz = P[2];   // centroid of seed 0 (index 0)
    int farthest = 0;

    for (int it = 0; it < N_SEEDS; ++it) {
        if (t == 0) seeds[b * N_SEEDS + it] = farthest;   // record OLD farthest

        float bestv = -1.0f, bx = 0.f, by = 0.f, bz = 0.f;
        int   besti = 0;
#define FSTEP(i) { const float dx = px##i - cx, dy = py##i - cy, dz = pz##i - cz; \
        const float d  = (dx*dx + dy*dy) + dz*dz; \
        const float nd = fminf(dd##i, d); dd##i = nd; \
        if (nd > bestv) { bestv = nd; besti = t*16 + (i); \
                          bx = px##i; by = py##i; bz = pz##i; } }
        FSTEP(0)  FSTEP(1)  FSTEP(2)  FSTEP(3)
        FSTEP(4)  FSTEP(5)  FSTEP(6)  FSTEP(7)
        FSTEP(8)  FSTEP(9)  FSTEP(10) FSTEP(11)
        FSTEP(12) FSTEP(13) FSTEP(14) FSTEP(15)

        // wave max (float), then locate lowest lane holding it (= lowest index)
        float wmax = bestv;
        for (int off = 32; off; off >>= 1)
            wmax = fmaxf(wmax, __shfl_xor(wmax, off));
        const u64 msk = __ballot(bestv == wmax);
        const int low = __ffsll((unsigned long long)msk) - 1;
        const int wi  = __shfl(besti, low);
        const float wx = __shfl(bx, low);
        const float wy = __shfl(by, low);
        const float wz = __shfl(bz, low);

        const int par = it & 1;
        if (lane == 0) {
            s_key[par][wid] = ((u64)__float_as_uint(wmax) << 32) | (u32)(~(u32)wi);
            s_cx[par][wid] = wx; s_cy[par][wid] = wy; s_cz[par][wid] = wz;
        }
        __syncthreads();

        // every lane reduces the 16 wave keys (xor-butterfly within 16-groups)
        u64 k = s_key[par][lane & 15];
        for (int off = 8; off; off >>= 1) {
            const u64 o = shfl_xor_u64(k, off);
            if (o > k) k = o;
        }
        const int widx = (int)(~(u32)k);    // winning point index (lowest on ties)
        farthest = widx;
        const int ww = widx >> 10;          // wave that owns it (1024 idx / wave)
        cx = s_cx[par][ww]; cy = s_cy[par][ww]; cz = s_cz[par][ww];
    }
}

// ---------------------------------------------------------------------------
// Kernel 2: per (batch, seed) 11 smallest distances via exact float-bit
// radix select: histogram on bits(d2)>>20 (2048 bins), uniform scan finds
// the bin holding the 11th smallest, candidates (~13 of 16384) collected
// from registers, O(n^2) rank-select in one wave. Distances computed once,
// kept in 64 statically-indexed registers. XCD-swizzled bid (round-3 win).
// ---------------------------------------------------------------------------
__global__ __launch_bounds__(256) void knn_kernel(const float* __restrict__ pcs,
                                                  const int* __restrict__ seeds,
                                                  float* __restrict__ topd) {
    const int bid = blockIdx.x;
    const int x   = bid & 7;          // XCD slot
    const int q   = bid >> 3;
    const int s   = q % 20;
    const int b   = x + 8 * (q / 20);
    const int blk = b * N_SEEDS + s;

    const float* __restrict__ P  = pcs + (size_t)b * N_PTS * 3;
    const float4* __restrict__ P4 = (const float4*)P;
    const int t    = threadIdx.x;
    const int lane = t & 63;
    const int sid  = seeds[blk];
    const float cx = P[sid*3], cy = P[sid*3+1], cz = P[sid*3+2];

    __shared__ u32   hist[NBIN];
    __shared__ u32   part[256];
    __shared__ float cand[CAP];
    __shared__ u32   cnt;

    // ---- phase 0: zero histogram + counter --------------------------------
#pragma unroll
    for (int i = 0; i < NBIN / 256; ++i) hist[t + i * 256] = 0u;
    if (t == 0) cnt = 0u;
    __syncthreads();

    // ---- phase 1: distances (held in regs) + histogram --------------------
    float dv[64];                     // statically indexed only -> registers
#pragma unroll
    for (int c = 0; c < 16; ++c) {
        const int i4 = (c * 256 + t) * 3;
        const float4 a = P4[i4], bq = P4[i4 + 1], cq = P4[i4 + 2];
        float dx, dy, dz;
        dx = a.x  - cx; dy = a.y  - cy; dz = a.z  - cz;
        dv[c*4+0] = fmaf(dz, dz, fmaf(dy, dy, dx * dx));
        dx = a.w  - cx; dy = bq.x - cy; dz = bq.y - cz;
        dv[c*4+1] = fmaf(dz, dz, fmaf(dy, dy, dx * dx));
        dx = bq.z - cx; dy = bq.w - cy; dz = cq.x - cz;
        dv[c*4+2] = fmaf(dz, dz, fmaf(dy, dy, dx * dx));
        dx = cq.y - cx; dy = cq.z - cy; dz = cq.w - cz;
        dv[c*4+3] = fmaf(dz, dz, fmaf(dy, dy, dx * dx));
        atomicAdd(&hist[__float_as_uint(dv[c*4+0]) >> 20], 1u);
        atomicAdd(&hist[__float_as_uint(dv[c*4+1]) >> 20], 1u);
        atomicAdd(&hist[__float_as_uint(dv[c*4+2]) >> 20], 1u);
        atomicAdd(&hist[__float_as_uint(dv[c*4+3]) >> 20], 1u);
    }
    __syncthreads();

    // ---- phase 2a: per-thread partial sums (8 bins each) ------------------
    {
        u32 s8 = 0;
#pragma unroll
        for (int i = 0; i < 8; ++i) s8 += hist[t * 8 + i];
        part[t] = s8;
    }
    __syncthreads();

    // ---- phase 2b: every wave finds the threshold bin (uniform) -----------
    u32 thr;
    {
        u32 s4 = part[lane*4] + part[lane*4+1] + part[lane*4+2] + part[lane*4+3];
        u32 cum = s4;
        for (int off = 1; off < 64; off <<= 1) {
            const u32 v = __shfl_up(cum, off);
            if (lane >= off) cum += v;
        }
        const u64 m = __ballot(cum >= (u32)KP1);
        const int L = __ffsll((unsigned long long)m) - 1;
        u32 below = __shfl(cum, L) - __shfl(s4, L);  // count in parts < 4L
        int p = L * 4;
        while (below + part[p] < (u32)KP1) { below += part[p]; ++p; }
        int bin = p * 8;
        while (below + hist[bin] < (u32)KP1) { below += hist[bin]; ++bin; }
        thr = (u32)(bin + 1) << 20;   // keys < thr are candidates (>= 11 of them)
    }

    // ---- phase 3: collect candidates from registers -----------------------
#pragma unroll
    for (int i = 0; i < 64; ++i) {
        if (__float_as_uint(dv[i]) < thr) {
            const u32 slot = atomicAdd(&cnt, 1u);
            if (slot < (u32)CAP) cand[slot] = dv[i];
        }
    }
    __syncthreads();

    // ---- phase 4: rank-select the 11 smallest among n candidates ----------
    if (t < 64) {
        const u32 n = min(cnt, (u32)CAP);
        for (u32 base = 0; base < n; base += 64) {
            const u32 idx = base + (u32)lane;
            const float v = (idx < n) ? cand[idx] : 3.0e38f;
            u32 r = 0;
            for (u32 j = 0; j < n; ++j) {
                const float w = cand[j];
                r += (w < v || (w == v && j < idx)) ? 1u : 0u;
            }
            if (idx < n && r < (u32)KP1)
                topd[blk * KP1 + r] = sqrtf(v);
        }
    }
}

// ---------------------------------------------------------------------------
// Kernel 3: stats (UNCHANGED). overall_mean over [:,:,1:], per-seed means,
// unbiased variance; fp64 accumulation.
// ---------------------------------------------------------------------------
__global__ __launch_bounds__(256) void stats_kernel(const float* __restrict__ topd,
                                                    float* __restrict__ out, int B) {
    const int pairs = B * N_SEEDS;
    const int total = pairs * KP1;
    const int t = threadIdx.x;
    __shared__ double red[256];
    __shared__ double om_s;

    double s1 = 0.0;
    for (int i = t; i < total; i += 256)
        if (i % KP1 != 0) s1 += (double)topd[i];
    red[t] = s1;
    __syncthreads();
    for (int off = 128; off > 0; off >>= 1) {
        if (t < off) red[t] += red[t + off];
        __syncthreads();
    }
    if (t == 0) om_s = red[0] / (double)(pairs * (KP1 - 1));
    __syncthreads();
    const double om = om_s;

    double sm = 0.0, sm2 = 0.0;
    for (int pr = t; pr < pairs; pr += 256) {
        double acc = 0.0;
        for (int j = 0; j < KP1; ++j) acc += (double)topd[pr * KP1 + j];
        const double m = acc / (om * (double)KP1);
        sm += m;
        sm2 += m * m;
    }
    red[t] = sm;
    __syncthreads();
    for (int off = 128; off > 0; off >>= 1) {
        if (t < off) red[t] += red[t + off];
        __syncthreads();
    }
    double Sm = 0.0;
    if (t == 0) Sm = red[0];
    __syncthreads();
    red[t] = sm2;
    __syncthreads();
    for (int off = 128; off > 0; off >>= 1) {
        if (t < off) red[t] += red[t + off];
        __syncthreads();
    }
    if (t == 0) {
        const double var = (red[0] - Sm * Sm / (double)pairs) / (double)(pairs - 1);
        out[0] = (float)var;
    }
}

// ---------------------------------------------------------------------------
extern "C" void kernel_launch(void* const* d_in, const int* in_sizes, int n_in,
                              void* d_out, int out_size, void* d_ws, size_t ws_size,
                              hipStream_t stream) {
    const float* pcs = (const float*)d_in[0];
    const int B = in_sizes[0] / (N_PTS * 3);

    int*   seeds = (int*)d_ws;
    float* topd  = (float*)((char*)d_ws + 8192);
    float* out   = (float*)d_out;

    fps_kernel<<<B, 1024, 0, stream>>>(pcs, seeds);
    knn_kernel<<<B * N_SEEDS, 256, 0, stream>>>(pcs, seeds, topd);
    stats_kernel<<<1, 256, 0, stream>>>(topd, out, B);
}